// Round 16
// baseline (1425.622 us; speedup 1.0000x reference)
//
#include <hip/hip_runtime.h>
#include <hip/hip_bf16.h>

typedef __attribute__((ext_vector_type(8))) short bf16x8;
typedef __attribute__((ext_vector_type(4))) float f32x4;

constexpr int NB = 64, NS = 512, ND = 512, NH = 1024;
constexpr int G4H = 4096;
constexpr int NWG = 256, NTHR = 512;
constexpr int PES = 20;            // part2 per-element stride (floats): 16 + 4 pad
constexpr int TRB = 3072;          // tile row stride bytes (512*2 + 1024*2)

__device__ inline unsigned short f2bf(float f) {
  union { float f; unsigned u; } v; v.f = f;
  unsigned r = v.u + 0x7FFFu + ((v.u >> 16) & 1u);  // RNE
  return (unsigned short)(r >> 16);
}
__device__ inline float sigmoidf_fast(float x) { return 1.0f / (1.0f + __expf(-x)); }
__device__ inline float tanhf_fast(float x) {
  float e = __expf(2.0f * x);
  return 1.0f - 2.0f / (e + 1.0f);
}
// XOR-swizzle intra-row byte offset (involution, applied on write AND read)
__device__ inline int swz(int row, int off) { return row * TRB + (off ^ ((row & 7) << 4)); }

// ---------------- prep: x -> bf16, init tagged h ping-pong ----------------
// hbuf[0] = 0x0000... : zeros, tag0-valid (= h(0) for t=0 readers)
// hbuf[1] = 0x00010001: tag1 pattern, INVALID for the first (tag0) use
__global__ void prep_kernel(const float* __restrict__ x,
                            unsigned short* __restrict__ xbf,
                            unsigned short* __restrict__ hbuf) {
  const int idx = blockIdx.x * blockDim.x + threadIdx.x;
  const int nthr = gridDim.x * blockDim.x;
  const int nh4 = NB * NH * 2 / 16;          // uint4 chunks per buffer
  uint4* h4 = (uint4*)hbuf;
  for (int i = idx; i < nh4; i += nthr) h4[i] = uint4{0, 0, 0, 0};
  for (int i = idx; i < nh4; i += nthr)
    h4[nh4 + i] = uint4{0x00010001u, 0x00010001u, 0x00010001u, 0x00010001u};
  const float4* x4 = (const float4*)x;
  ushort4* xo = (ushort4*)xbf;
  const int n4 = NB * NS * ND / 4;
  for (int i = idx; i < n4; i += nthr) {
    float4 v = x4[i];
    ushort4 o;
    o.x = f2bf(v.x); o.y = f2bf(v.y); o.z = f2bf(v.z); o.w = f2bf(v.w);
    xo[i] = o;
  }
}

// ---------------- main persistent kernel (r15 + load-delay + part transpose) ----
__global__ __launch_bounds__(NTHR)
void lstm_kernel(const float* __restrict__ Wih,
                 const float* __restrict__ Whh,
                 const float* __restrict__ bias,
                 const unsigned short* __restrict__ xbf,
                 unsigned short* __restrict__ hbuf,   // 2 ping-pong NB*NH bf16 (LLC)
                 float* __restrict__ out)
{
  const int tid  = threadIdx.x;
  const int wg   = blockIdx.x;
  const int wave = tid >> 6;
  const int lane = tid & 63;
  const int bb   = wg >> 6;       // batch block (hb-major: XCD-chunk locality)
  const int hb   = wg & 63;       // hidden block (16 cols)
  const int gp   = wave & 1;      // gate pair: 0 -> {i,f}, 1 -> {g,o}
  const int q    = wave >> 1;     // K quarter (x-ksteps 4q..4q+3, h-ksteps 8q..8q+7)

  __shared__ unsigned short tile[16 * 1536];  // [16][512 x | 1024 h] bf16, swizzled
  __shared__ float part2[256 * PES];          // [elem][16 gatesrc + pad] (20KB)
  __shared__ float c_state[256];

  if (tid < 256) c_state[tid] = 0.0f;

  // ---------- one-time weight B-frag gather (col = lane&15, k = kbase+(lane>>4)*8+j) ----
  const int kg0  = (lane >> 4) << 3;
  const int colb = (hb << 4) + (lane & 15);
  bf16x8 wx[2][4], wh[2][8];
#pragma unroll
  for (int gg = 0; gg < 2; ++gg) {
    const int col = ((gp * 2 + gg) << 10) + colb;
#pragma unroll
    for (int s = 0; s < 4; ++s) {
      const int k0 = (q * 4 + s) * 32 + kg0;
#pragma unroll
      for (int j = 0; j < 8; ++j)
        wx[gg][s][j] = (short)f2bf(Wih[(size_t)(k0 + j) * G4H + col]);
    }
#pragma unroll
    for (int u = 0; u < 8; ++u) {
      const int k0 = (q * 8 + u) * 32 + kg0;
#pragma unroll
      for (int j = 0; j < 8; ++j)
        wh[gg][u][j] = (short)f2bf(Whh[(size_t)(k0 + j) * G4H + col]);
    }
  }

  // ---------- prologue: stage x(0); zero h region ----------
  for (int c = tid; c < 1024; c += NTHR) {       // 16 rows x 64 slots(16B) of x
    const int row = c >> 6, sl = c & 63;
    const unsigned short* src = xbf + (size_t)(bb * 16 + row) * (NS * ND) + sl * 8;
    *(uint4*)((char*)tile + swz(row, sl * 16)) = *(const uint4*)src;
  }
  for (int c = tid; c < 2048; c += NTHR) {       // 16 rows x 128 slots of h
    const int row = c >> 7, sl = c & 127;
    *(uint4*)((char*)tile + swz(row, 1024 + sl * 16)) = uint4{0, 0, 0, 0};
  }
  __syncthreads();

  const int arow = lane & 15;
  float* ht_out = out + (size_t)NB * NS * NH;
  float* ct_out = ht_out + NB * NH;

  for (int t = 0; t < NS; ++t) {
    // ---- P2 FIRST: x-part MFMAs (delays h-load issue so first read is fresh) ----
    f32x4 a0 = {0.f, 0.f, 0.f, 0.f}, a1 = {0.f, 0.f, 0.f, 0.f};
#pragma unroll
    for (int s = 0; s < 4; ++s) {
      const int off = ((q * 4 + s) * 32 + kg0) * 2;
      bf16x8 af = *(const bf16x8*)((const char*)tile + swz(arow, off));
      a0 = __builtin_amdgcn_mfma_f32_16x16x32_bf16(af, wx[0][s], a0, 0, 0, 0);
      a1 = __builtin_amdgcn_mfma_f32_16x16x32_bf16(af, wx[1][s], a1, 0, 0, 0);
    }
    __builtin_amdgcn_sched_barrier(0);  // pin: h loads issue AFTER the x MFMAs

    // ---- P1: issue h(t) loads (4 x 16B per thread) ----
    constexpr unsigned long long M = 0x0000000100000001ull;
    const unsigned long long T = ((t >> 1) & 1) ? M : 0ull;
    unsigned long long hq0[4], hq1[4];
    const unsigned long long* hp[4];
    if (t > 0) {
      const unsigned short* hbase = hbuf + (size_t)(t & 1) * (NB * NH);
#pragma unroll
      for (int u = 0; u < 4; ++u) {
        const int row = 2 * wave + (u >> 1);
        const int sl  = (u & 1) * 64 + lane;
        hp[u] = (const unsigned long long*)(hbase + (size_t)(bb * 16 + row) * NH + sl * 8);
        hq0[u] = __hip_atomic_load(hp[u],     __ATOMIC_RELAXED, __HIP_MEMORY_SCOPE_AGENT);
        hq1[u] = __hip_atomic_load(hp[u] + 1, __ATOMIC_RELAXED, __HIP_MEMORY_SCOPE_AGENT);
      }
    }

    // ---- P3: validate tags (poll = reload stale chunks) + ds_write h slice ----
    if (t > 0) {
      while (true) {
        int stale = 0;
#pragma unroll
        for (int u = 0; u < 4; ++u)
          if ((((hq0[u] ^ T) | (hq1[u] ^ T)) & M) != 0ull) stale |= (1 << u);
        if (__all(stale == 0)) break;
#pragma unroll
        for (int u = 0; u < 4; ++u)
          if (stale & (1 << u)) {
            hq0[u] = __hip_atomic_load(hp[u],     __ATOMIC_RELAXED, __HIP_MEMORY_SCOPE_AGENT);
            hq1[u] = __hip_atomic_load(hp[u] + 1, __ATOMIC_RELAXED, __HIP_MEMORY_SCOPE_AGENT);
          }
      }
#pragma unroll
      for (int u = 0; u < 4; ++u) {
        const int row = 2 * wave + (u >> 1);
        const int sl  = (u & 1) * 64 + lane;
        uint4 v;
        v.x = (unsigned int)hq0[u];
        v.y = (unsigned int)(hq0[u] >> 32);
        v.z = (unsigned int)hq1[u];
        v.w = (unsigned int)(hq1[u] >> 32);
        *(uint4*)((char*)tile + swz(row, 1024 + sl * 16)) = v;
      }
    }
    __syncthreads();  // B_A: h region ready

    // ---- P5: h-part MFMAs ----
#pragma unroll
    for (int u = 0; u < 8; ++u) {
      const int off = 1024 + ((q * 8 + u) * 32 + kg0) * 2;
      bf16x8 af = *(const bf16x8*)((const char*)tile + swz(arow, off));
      a0 = __builtin_amdgcn_mfma_f32_16x16x32_bf16(af, wh[0][u], a0, 0, 0, 0);
      a1 = __builtin_amdgcn_mfma_f32_16x16x32_bf16(af, wh[1][u], a1, 0, 0, 0);
    }

    // ---- P6: transposed partials: part2[elem][wave*2+gg] ----
    {
      const int r0 = (lane >> 4) << 2;
      const int cc = lane & 15;
#pragma unroll
      for (int j = 0; j < 4; ++j) {
        const int elem = (r0 + j) * 16 + cc;
        part2[elem * PES + wave * 2 + 0] = a0[j];
        part2[elem * PES + wave * 2 + 1] = a1[j];
      }
    }
    __syncthreads();  // B_B: parts ready, tile-x free

    // ---- P7: epilogue (waves 0-3) || x(t+1) staging (waves 4-7) ----
    if (tid < 256) {
      const int ec = tid & 15;
      const int er = tid >> 4;
      // 4 x ds_read_b128: this thread's 16 gate-partials are contiguous
      const float4* pr = (const float4*)(part2 + tid * PES);
      float4 s0 = pr[0], s1 = pr[1], s2 = pr[2], s3 = pr[3];
      float4 sg = (s0 + s1) + (s2 + s3);   // sg[g] = sum over 4 K-quarters, gate g
      const float pre0 = sg.x + bias[(0 << 10) + (hb << 4) + ec];
      const float pre1 = sg.y + bias[(1 << 10) + (hb << 4) + ec];
      const float pre2 = sg.z + bias[(2 << 10) + (hb << 4) + ec];
      const float pre3 = sg.w + bias[(3 << 10) + (hb << 4) + ec];
      const float it = sigmoidf_fast(pre0);
      const float ft = sigmoidf_fast(pre1);
      const float gt = tanhf_fast(pre2);
      const float ot = sigmoidf_fast(pre3);
      const float cn = ft * c_state[tid] + it * gt;
      c_state[tid] = cn;
      const float hn = ot * tanhf_fast(cn);
      const int row  = bb * 16 + er;
      const int hcol = (hb << 4) + ec;
      const size_t ooff = (size_t)row * (NS * NH) + (size_t)t * NH + hcol;
      if (t == NS - 1) {
        out[ooff] = hn;
        ht_out[row * NH + hcol] = hn;
        ct_out[row * NH + hcol] = cn;
      } else {
        // tagged bf16 pair -> one fire-and-forget sc1 store (no drain, no flag)
        const unsigned int tagw = (unsigned int)(((t + 1) >> 1) & 1);
        unsigned int my  = (unsigned int)f2bf(hn);
        unsigned int pa  = (unsigned int)__shfl_xor((int)my, 1, 64);  // odd col, untagged
        if ((tid & 1) == 0) {
          unsigned int myt = (my & ~1u) | tagw;   // even col carries the tag bit
          unsigned int* p = (unsigned int*)(hbuf + (size_t)((t + 1) & 1) * (NB * NH)
                                                 + (size_t)row * NH + hcol);
          __hip_atomic_store(p, myt | (pa << 16), __ATOMIC_RELAXED, __HIP_MEMORY_SCOPE_AGENT);
        }
        __builtin_nontemporal_store(hn, &out[ooff]);
      }
    } else if (t < NS - 1) {
      // x(t+1): 1024 chunks of 16B over 256 threads
      for (int c = tid - 256; c < 1024; c += 256) {
        const int row = c >> 6, sl = c & 63;
        const unsigned short* src = xbf + (size_t)(bb * 16 + row) * (NS * ND)
                                        + (size_t)(t + 1) * ND + sl * 8;
        *(uint4*)((char*)tile + swz(row, sl * 16)) = *(const uint4*)src;
      }
    }
    if (t < NS - 1) __syncthreads();  // B_C: x staged before next P2 reads it
  }
}

extern "C" void kernel_launch(void* const* d_in, const int* in_sizes, int n_in,
                              void* d_out, int out_size, void* d_ws, size_t ws_size,
                              hipStream_t stream) {
  const float* x    = (const float*)d_in[0];
  const float* wih  = (const float*)d_in[1];
  const float* whh  = (const float*)d_in[2];
  const float* bias = (const float*)d_in[3];
  float* out = (float*)d_out;

  // ws layout: [hbuf 2*NB*NH bf16 = 256KB][xbf NB*NS*ND bf16 = 32MB]
  unsigned short* hbuf = (unsigned short*)d_ws;
  unsigned short* xbf  = (unsigned short*)((char*)d_ws + (size_t)2 * NB * NH * 2);

  prep_kernel<<<1024, 256, 0, stream>>>(x, xbf, hbuf);

  void* args[] = { (void*)&wih, (void*)&whh, (void*)&bias,
                   (void*)&xbf, (void*)&hbuf, (void*)&out };
  hipLaunchCooperativeKernel((const void*)lstm_kernel, dim3(NWG), dim3(NTHR),
                             args, 0, stream);
}